// Round 1
// baseline (984.278 us; speedup 1.0000x reference)
//
#include <hip/hip_runtime.h>

#define Bb 16
#define Nn 200
#define NM1 199
#define Uu 64
#define EPSBN 1e-5f
#define SLOPE 0.01f
#define SPREAD 64
#define CH 16

__device__ __forceinline__ float lrelu(float v) { return v > 0.f ? v : SLOPE * v; }
__device__ __forceinline__ int dstcol(int n, int k) { return k < n ? k : k + 1; }

// h = lrelu(x @ v_lin0_w + v_lin0_b)
__global__ void k_h0(const float* __restrict__ x, const float* __restrict__ w0,
                     const float* __restrict__ b0, float* __restrict__ h) {
    int idx = blockIdx.x * blockDim.x + threadIdx.x;
    if (idx >= Bb * Nn * Uu) return;
    int bn = idx / Uu, u = idx % Uu;
    float v = fmaf(x[bn * 2], w0[u], fmaf(x[bn * 2 + 1], w0[Uu + u], b0[u]));
    h[idx] = lrelu(v);
}

// x1..x4 = h @ v_wk[i] + v_bk[i]; block 0 also zeros the stats spread array
__global__ void k_xvec(const float* __restrict__ h,
                       const float* __restrict__ w1, const float* __restrict__ b1,
                       const float* __restrict__ w2, const float* __restrict__ b2,
                       const float* __restrict__ w3, const float* __restrict__ b3,
                       const float* __restrict__ w4, const float* __restrict__ b4,
                       float* __restrict__ x1, float* __restrict__ x2,
                       float* __restrict__ x3, float* __restrict__ x4,
                       float* __restrict__ spread) {
    __shared__ float hrow[Uu];
    int bn = blockIdx.x;
    int u = threadIdx.x;
    if (blockIdx.x == 0) {
        for (int t = u; t < SPREAD * 128; t += Uu) spread[t] = 0.f;
    }
    hrow[u] = h[bn * Uu + u];
    __syncthreads();
    float a1 = b1[u], a2 = b2[u], a3 = b3[u], a4 = b4[u];
#pragma unroll 8
    for (int j = 0; j < Uu; ++j) {
        float hv = hrow[j];
        a1 = fmaf(hv, w1[j * Uu + u], a1);
        a2 = fmaf(hv, w2[j * Uu + u], a2);
        a3 = fmaf(hv, w3[j * Uu + u], a3);
        a4 = fmaf(hv, w4[j * Uu + u], a4);
    }
    x1[bn * Uu + u] = a1;
    x2[bn * Uu + u] = a2;
    x3[bn * Uu + u] = a3;
    x4[bn * Uu + u] = a4;
}

// Pass 1: accumulate BN stats of z = w@e_w + e_b + x3 + x4[DST]; pooled = max_k sig(w)*x2[DST]
template <bool FIRST, bool POOL>
__global__ __launch_bounds__(256, 3) void k_pass1(
    const float* __restrict__ w, const float* __restrict__ adj,
    const float* __restrict__ ew, const float* __restrict__ ebias,
    const float* __restrict__ e0w, const float* __restrict__ e0b,
    const float* __restrict__ x2, const float* __restrict__ x3,
    const float* __restrict__ x4, float* __restrict__ pooled,
    float* __restrict__ spread) {
    __shared__ __align__(16) float lsw[CH][Uu];
    __shared__ float red[4][Uu];
    int bn = blockIdx.x;
    int b = bn / Nn, n = bn % Nn;
    int tid = threadIdx.x;
    int u = tid & 63;
    int wave = tid >> 6;
    float Ecol[Uu];
#pragma unroll
    for (int j = 0; j < Uu; ++j) Ecol[j] = ew[j * Uu + u];
    float cvec = ebias[u] + x3[bn * Uu + u];
    float e0wv = 0.f, e0bv = 0.f;
    if (FIRST) { e0wv = e0w[u]; e0bv = e0b[u]; }
    const float* adjrow = adj + (size_t)bn * Nn;
    const float* wbase = w + (size_t)bn * NM1 * Uu;
    float sum = 0.f, sumsq = 0.f, pm = -3.402823e38f;

    for (int c0 = 0; c0 < NM1; c0 += CH) {
        __syncthreads();
#pragma unroll
        for (int s = 0; s < (CH * Uu) / 256; ++s) {
            int r = wave + s * 4;
            int kk = c0 + r;
            if (kk < NM1) {
                float val;
                if (FIRST) {
                    float raw = adjrow[dstcol(n, kk)];
                    val = lrelu(fmaf(raw, e0wv, e0bv));
                } else {
                    val = wbase[(size_t)kk * Uu + u];
                }
                lsw[r][u] = val;
            }
        }
        __syncthreads();
        for (int rr = wave; rr < CH; rr += 4) {
            int kk = c0 + rr;
            if (kk >= NM1) break;
            int dst = dstcol(n, kk);
            const float* row = lsw[rr];
            float acc = 0.f;
#pragma unroll
            for (int j4 = 0; j4 < 16; ++j4) {
                float4 wv = ((const float4*)row)[j4];
                acc = fmaf(wv.x, Ecol[4 * j4 + 0], acc);
                acc = fmaf(wv.y, Ecol[4 * j4 + 1], acc);
                acc = fmaf(wv.z, Ecol[4 * j4 + 2], acc);
                acc = fmaf(wv.w, Ecol[4 * j4 + 3], acc);
            }
            float z = acc + cvec + x4[((size_t)b * Nn + dst) * Uu + u];
            sum += z;
            sumsq = fmaf(z, z, sumsq);
            if (POOL) {
                float wv = row[u];
                float sg = 1.f / (1.f + __expf(-wv));
                float xv = x2[((size_t)b * Nn + dst) * Uu + u];
                pm = fmaxf(pm, sg * xv);
            }
        }
    }
    __syncthreads();
    red[wave][u] = sum;
    __syncthreads();
    if (wave == 0) {
        float s = red[0][u] + red[1][u] + red[2][u] + red[3][u];
        atomicAdd(&spread[(bn & (SPREAD - 1)) * 128 + u], s);
    }
    __syncthreads();
    red[wave][u] = sumsq;
    __syncthreads();
    if (wave == 0) {
        float s = red[0][u] + red[1][u] + red[2][u] + red[3][u];
        atomicAdd(&spread[(bn & (SPREAD - 1)) * 128 + 64 + u], s);
    }
    if (POOL) {
        __syncthreads();
        red[wave][u] = pm;
        __syncthreads();
        if (wave == 0) {
            float m = fmaxf(fmaxf(red[0][u], red[1][u]), fmaxf(red[2][u], red[3][u]));
            pooled[(size_t)bn * Uu + u] = m;
        }
    }
}

// finalize w-path BN: wss[u]=scale, wss[64+u]=shift
__global__ void k_finw(const float* __restrict__ spread, const float* __restrict__ g,
                       const float* __restrict__ bb, float* __restrict__ wss) {
    int u = threadIdx.x;
    float s = 0.f, sq = 0.f;
    for (int p = 0; p < SPREAD; ++p) {
        s += spread[p * 128 + u];
        sq += spread[p * 128 + 64 + u];
    }
    const float Mf = (float)((size_t)Bb * Nn * NM1);
    float mean = s / Mf;
    float var = fmaxf(sq / Mf - mean * mean, 0.f);
    float inv = rsqrtf(var + EPSBN);
    float scale = g[u] * inv;
    wss[u] = scale;
    wss[64 + u] = bb[u] - mean * scale;
}

// h update: h += lrelu(bn(x1 + pooled)); one block per channel
__global__ void k_hup(const float* __restrict__ x1, const float* __restrict__ pooled,
                      const float* __restrict__ g, const float* __restrict__ bb,
                      float* __restrict__ h) {
    __shared__ float red[256], red2[256];
    int ch = blockIdx.x;
    int t = threadIdx.x;
    float s = 0.f, sq = 0.f;
    for (int bn = t; bn < Bb * Nn; bn += 256) {
        float v = x1[bn * Uu + ch] + pooled[bn * Uu + ch];
        s += v;
        sq = fmaf(v, v, sq);
    }
    red[t] = s;
    red2[t] = sq;
    __syncthreads();
    for (int off = 128; off; off >>= 1) {
        if (t < off) { red[t] += red[t + off]; red2[t] += red2[t + off]; }
        __syncthreads();
    }
    const float Mf = (float)(Bb * Nn);
    float mean = red[0] / Mf;
    float var = fmaxf(red2[0] / Mf - mean * mean, 0.f);
    float inv = rsqrtf(var + EPSBN);
    float scale = g[ch] * inv;
    float shift = bb[ch] - mean * scale;
    for (int bn = t; bn < Bb * Nn; bn += 256) {
        float v = x1[bn * Uu + ch] + pooled[bn * Uu + ch];
        h[bn * Uu + ch] += lrelu(fmaf(v, scale, shift));
    }
}

// Pass 2: recompute z, apply BN+lrelu+residual; write w (or final dot+scatter when LAST)
template <bool FIRST, bool LAST>
__global__ __launch_bounds__(256, 3) void k_pass2(
    float* __restrict__ w, const float* __restrict__ adj,
    const float* __restrict__ ew, const float* __restrict__ ebias,
    const float* __restrict__ e0w, const float* __restrict__ e0b,
    const float* __restrict__ x3, const float* __restrict__ x4,
    const float* __restrict__ wss, const float* __restrict__ elw,
    const float* __restrict__ elb, float* __restrict__ out) {
    __shared__ __align__(16) float lsw[CH][Uu];
    int bn = blockIdx.x;
    int b = bn / Nn, n = bn % Nn;
    int tid = threadIdx.x;
    int u = tid & 63;
    int wave = tid >> 6;
    float Ecol[Uu];
#pragma unroll
    for (int j = 0; j < Uu; ++j) Ecol[j] = ew[j * Uu + u];
    float cvec = ebias[u] + x3[bn * Uu + u];
    float scale = wss[u], shift = wss[64 + u];
    float e0wv = 0.f, e0bv = 0.f;
    if (FIRST) { e0wv = e0w[u]; e0bv = e0b[u]; }
    float elwv = 0.f, elbv = 0.f;
    if (LAST) { elwv = elw[u]; elbv = elb[0]; }
    const float* adjrow = adj + (size_t)bn * Nn;
    float* wbase = w + (size_t)bn * NM1 * Uu;

    for (int c0 = 0; c0 < NM1; c0 += CH) {
        __syncthreads();
#pragma unroll
        for (int s = 0; s < (CH * Uu) / 256; ++s) {
            int r = wave + s * 4;
            int kk = c0 + r;
            if (kk < NM1) {
                float val;
                if (FIRST) {
                    float raw = adjrow[dstcol(n, kk)];
                    val = lrelu(fmaf(raw, e0wv, e0bv));
                } else {
                    val = wbase[(size_t)kk * Uu + u];
                }
                lsw[r][u] = val;
            }
        }
        __syncthreads();
        for (int rr = wave; rr < CH; rr += 4) {
            int kk = c0 + rr;
            if (kk >= NM1) break;
            int dst = dstcol(n, kk);
            const float* row = lsw[rr];
            float acc = 0.f;
#pragma unroll
            for (int j4 = 0; j4 < 16; ++j4) {
                float4 wv = ((const float4*)row)[j4];
                acc = fmaf(wv.x, Ecol[4 * j4 + 0], acc);
                acc = fmaf(wv.y, Ecol[4 * j4 + 1], acc);
                acc = fmaf(wv.z, Ecol[4 * j4 + 2], acc);
                acc = fmaf(wv.w, Ecol[4 * j4 + 3], acc);
            }
            float z = acc + cvec + x4[((size_t)b * Nn + dst) * Uu + u];
            float wold = row[u];
            float wnew = wold + lrelu(fmaf(z, scale, shift));
            if (!LAST) {
                wbase[(size_t)kk * Uu + u] = wnew;
            } else {
                float t = wnew * elwv;
#pragma unroll
                for (int off = 32; off; off >>= 1) t += __shfl_xor(t, off, 64);
                if (u == 0) out[(size_t)bn * Nn + dst] = t + elbv;
            }
        }
    }
    if (LAST && tid == 0) out[(size_t)bn * Nn + n] = 0.f;
}

extern "C" void kernel_launch(void* const* d_in, const int* in_sizes, int n_in,
                              void* d_out, int out_size, void* d_ws, size_t ws_size,
                              hipStream_t stream) {
    const float* x = (const float*)d_in[0];
    const float* adj = (const float*)d_in[1];
    const float* vl0w = (const float*)d_in[2];
    const float* vl0b = (const float*)d_in[3];
    const float* vw1 = (const float*)d_in[4];
    const float* vb1 = (const float*)d_in[5];
    const float* vw2 = (const float*)d_in[6];
    const float* vb2 = (const float*)d_in[7];
    const float* vw3 = (const float*)d_in[8];
    const float* vb3 = (const float*)d_in[9];
    const float* vw4 = (const float*)d_in[10];
    const float* vb4 = (const float*)d_in[11];
    const float* vbng = (const float*)d_in[12];
    const float* vbnb = (const float*)d_in[13];
    const float* e0w = (const float*)d_in[14];
    const float* e0b = (const float*)d_in[15];
    const float* ew = (const float*)d_in[16];
    const float* eb = (const float*)d_in[17];
    const float* ebng = (const float*)d_in[18];
    const float* ebnb = (const float*)d_in[19];
    const float* elw = (const float*)d_in[20];
    const float* elb = (const float*)d_in[21];
    float* out = (float*)d_out;

    float* ws = (float*)d_ws;
    float* w = ws;                        // 40,755,200 floats
    float* h = ws + 40755200;             // 204,800
    float* x1 = h + 204800;
    float* x2b = x1 + 204800;
    float* x3b = x2b + 204800;
    float* x4b = x3b + 204800;
    float* pooled = x4b + 204800;
    float* spread = pooled + 204800;      // SPREAD*128
    float* wss = spread + SPREAD * 128;   // 128

    const int GRID = Bb * Nn;  // 3200

    k_h0<<<800, 256, 0, stream>>>(x, vl0w, vl0b, h);

    // ---- layer 0 ----
    k_xvec<<<GRID, 64, 0, stream>>>(h, vw1, vb1, vw2, vb2, vw3, vb3, vw4, vb4,
                                    x1, x2b, x3b, x4b, spread);
    k_pass1<true, true><<<GRID, 256, 0, stream>>>(w, adj, ew, eb, e0w, e0b, x2b,
                                                  x3b, x4b, pooled, spread);
    k_finw<<<1, 64, 0, stream>>>(spread, ebng, ebnb, wss);
    k_hup<<<64, 256, 0, stream>>>(x1, pooled, vbng, vbnb, h);
    k_pass2<true, false><<<GRID, 256, 0, stream>>>(w, adj, ew, eb, e0w, e0b, x3b,
                                                   x4b, wss, elw, elb, out);

    // ---- layer 1 ----
    k_xvec<<<GRID, 64, 0, stream>>>(h, vw1 + 4096, vb1 + 64, vw2 + 4096, vb2 + 64,
                                    vw3 + 4096, vb3 + 64, vw4 + 4096, vb4 + 64,
                                    x1, x2b, x3b, x4b, spread);
    k_pass1<false, true><<<GRID, 256, 0, stream>>>(w, adj, ew + 4096, eb + 64, e0w,
                                                   e0b, x2b, x3b, x4b, pooled, spread);
    k_finw<<<1, 64, 0, stream>>>(spread, ebng + 64, ebnb + 64, wss);
    k_hup<<<64, 256, 0, stream>>>(x1, pooled, vbng + 64, vbnb + 64, h);
    k_pass2<false, false><<<GRID, 256, 0, stream>>>(w, adj, ew + 4096, eb + 64, e0w,
                                                    e0b, x3b, x4b, wss, elw, elb, out);

    // ---- layer 2 ----
    k_xvec<<<GRID, 64, 0, stream>>>(h, vw1 + 8192, vb1 + 128, vw2 + 8192, vb2 + 128,
                                    vw3 + 8192, vb3 + 128, vw4 + 8192, vb4 + 128,
                                    x1, x2b, x3b, x4b, spread);
    k_pass1<false, false><<<GRID, 256, 0, stream>>>(w, adj, ew + 8192, eb + 128, e0w,
                                                    e0b, x2b, x3b, x4b, pooled, spread);
    k_finw<<<1, 64, 0, stream>>>(spread, ebng + 128, ebnb + 128, wss);
    k_pass2<false, true><<<GRID, 256, 0, stream>>>(w, adj, ew + 8192, eb + 128, e0w,
                                                   e0b, x3b, x4b, wss, elw, elb, out);
}

// Round 2
// 527.826 us; speedup vs baseline: 1.8648x; 1.8648x over previous
//
#include <hip/hip_runtime.h>

#define Bb 16
#define Nn 200
#define NM1 199
#define Uu 64
#define EPSBN 1e-5f
#define SLOPE 0.01f
#define SPREAD 64

typedef _Float16 f16;
typedef __attribute__((ext_vector_type(8))) _Float16 f16x8;
typedef __attribute__((ext_vector_type(2))) _Float16 f16x2;
typedef __attribute__((ext_vector_type(4))) float floatx4;

#define ET_STRIDE 72  // 64 + 8 f16 pad -> 144 B rows, conflict-free b128 frag reads

__device__ __forceinline__ float lrelu(float v) { return v > 0.f ? v : SLOPE * v; }
__device__ __forceinline__ int dstcol(int n, int k) { return k < n ? k : k + 1; }

// h = lrelu(x @ v_lin0_w + v_lin0_b)
__global__ void k_h0(const float* __restrict__ x, const float* __restrict__ w0,
                     const float* __restrict__ b0, float* __restrict__ h) {
    int idx = blockIdx.x * blockDim.x + threadIdx.x;
    if (idx >= Bb * Nn * Uu) return;
    int bn = idx / Uu, u = idx % Uu;
    float v = fmaf(x[bn * 2], w0[u], fmaf(x[bn * 2 + 1], w0[Uu + u], b0[u]));
    h[idx] = lrelu(v);
}

// x1..x4 = h @ v_wk[i] + v_bk[i]; block 0 also zeros the stats spread array
__global__ void k_xvec(const float* __restrict__ h,
                       const float* __restrict__ w1, const float* __restrict__ b1,
                       const float* __restrict__ w2, const float* __restrict__ b2,
                       const float* __restrict__ w3, const float* __restrict__ b3,
                       const float* __restrict__ w4, const float* __restrict__ b4,
                       float* __restrict__ x1, float* __restrict__ x2,
                       float* __restrict__ x3, float* __restrict__ x4,
                       float* __restrict__ spread) {
    __shared__ float hrow[Uu];
    int bn = blockIdx.x;
    int u = threadIdx.x;
    if (blockIdx.x == 0) {
        for (int t = u; t < SPREAD * 128; t += Uu) spread[t] = 0.f;
    }
    hrow[u] = h[bn * Uu + u];
    __syncthreads();
    float a1 = b1[u], a2 = b2[u], a3 = b3[u], a4 = b4[u];
#pragma unroll 8
    for (int j = 0; j < Uu; ++j) {
        float hv = hrow[j];
        a1 = fmaf(hv, w1[j * Uu + u], a1);
        a2 = fmaf(hv, w2[j * Uu + u], a2);
        a3 = fmaf(hv, w3[j * Uu + u], a3);
        a4 = fmaf(hv, w4[j * Uu + u], a4);
    }
    x1[bn * Uu + u] = a1;
    x2[bn * Uu + u] = a2;
    x3[bn * Uu + u] = a3;
    x4[bn * Uu + u] = a4;
}

// --- MFMA pass 1: BN stats of z = w@E + eb + x3 + x4[dst]; optional pooled ---
template <bool FIRST, bool POOL>
__global__ __launch_bounds__(256, 4) void k_p1(
    const float* __restrict__ w, const float* __restrict__ adj,
    const float* __restrict__ ew, const float* __restrict__ ebias,
    const float* __restrict__ e0w, const float* __restrict__ e0b,
    const float* __restrict__ x2, const float* __restrict__ x3,
    const float* __restrict__ x4, float* __restrict__ pooled,
    float* __restrict__ spread) {
    __shared__ __align__(16) f16 Et[Uu * ET_STRIDE];
    __shared__ float c2[Uu];
    __shared__ float sred[128];
    __shared__ float pred[4][Uu];
    __shared__ float e0wL[Uu], e0bL[Uu];

    int bn = blockIdx.x;
    int b = bn / Nn, n = bn % Nn;
    int tid = threadIdx.x;
    int l = tid & 63, wv = tid >> 6;
    int r16 = l & 15, q = l >> 4;

    {   // stage E^T (f16) into LDS
        int u = tid & 63, g = tid >> 6;
#pragma unroll
        for (int pp = 0; pp < 8; ++pp) {
            int jp = g + pp * 4;  // f16 pair index 0..31
            f16x2 pk;
            pk.x = (f16)ew[(2 * jp) * Uu + u];
            pk.y = (f16)ew[(2 * jp + 1) * Uu + u];
            *(f16x2*)&Et[u * ET_STRIDE + 2 * jp] = pk;
        }
    }
    if (tid < Uu) c2[tid] = ebias[tid] + x3[(size_t)bn * Uu + tid];
    if (tid < 128) sred[tid] = 0.f;
    if (FIRST && tid < Uu) { e0wL[tid] = e0w[tid]; e0bL[tid] = e0b[tid]; }
    __syncthreads();

    // hoist B fragments: Bf[khalf][ntile]
    f16x8 Bf[2][4];
#pragma unroll
    for (int hh = 0; hh < 2; ++hh)
#pragma unroll
        for (int nt = 0; nt < 4; ++nt)
            Bf[hh][nt] = *(const f16x8*)&Et[(nt * 16 + r16) * ET_STRIDE + hh * 32 + q * 8];

    const float* adjrow = adj + (size_t)bn * Nn;
    float sum[4] = {0.f, 0.f, 0.f, 0.f};
    float sq[4] = {0.f, 0.f, 0.f, 0.f};

    for (int mt = wv; mt < 13; mt += 4) {
        int row = mt * 16 + r16;
        bool rv = row < NM1;
        f16x8 A0 = (f16x8){0, 0, 0, 0, 0, 0, 0, 0};
        f16x8 A1 = (f16x8){0, 0, 0, 0, 0, 0, 0, 0};
        if (rv) {
            if (FIRST) {
                float av = adjrow[dstcol(n, row)];
#pragma unroll
                for (int j = 0; j < 8; ++j) {
                    A0[j] = (f16)lrelu(fmaf(av, e0wL[q * 8 + j], e0bL[q * 8 + j]));
                    A1[j] = (f16)lrelu(fmaf(av, e0wL[32 + q * 8 + j], e0bL[32 + q * 8 + j]));
                }
            } else {
                const float* wrow = w + ((size_t)bn * NM1 + row) * Uu;
                float4 p0 = *(const float4*)(wrow + q * 8);
                float4 p1 = *(const float4*)(wrow + q * 8 + 4);
                float4 p2 = *(const float4*)(wrow + 32 + q * 8);
                float4 p3 = *(const float4*)(wrow + 32 + q * 8 + 4);
                A0[0] = (f16)p0.x; A0[1] = (f16)p0.y; A0[2] = (f16)p0.z; A0[3] = (f16)p0.w;
                A0[4] = (f16)p1.x; A0[5] = (f16)p1.y; A0[6] = (f16)p1.z; A0[7] = (f16)p1.w;
                A1[0] = (f16)p2.x; A1[1] = (f16)p2.y; A1[2] = (f16)p2.z; A1[3] = (f16)p2.w;
                A1[4] = (f16)p3.x; A1[5] = (f16)p3.y; A1[6] = (f16)p3.z; A1[7] = (f16)p3.w;
            }
        }
        floatx4 acc[4];
#pragma unroll
        for (int nt = 0; nt < 4; ++nt) {
            acc[nt] = (floatx4){0.f, 0.f, 0.f, 0.f};
            acc[nt] = __builtin_amdgcn_mfma_f32_16x16x32_f16(A0, Bf[0][nt], acc[nt], 0, 0, 0);
            acc[nt] = __builtin_amdgcn_mfma_f32_16x16x32_f16(A1, Bf[1][nt], acc[nt], 0, 0, 0);
        }
        // epilogue: C layout col=l&15, row=q*4+rr
#pragma unroll
        for (int rr = 0; rr < 4; ++rr) {
            int k = mt * 16 + q * 4 + rr;
            if (k < NM1) {
                int dst = dstcol(n, k);
                const float* x4r = x4 + (size_t)(b * Nn + dst) * Uu;
#pragma unroll
                for (int nt = 0; nt < 4; ++nt) {
                    int u = nt * 16 + r16;
                    float z = acc[nt][rr] + c2[u] + x4r[u];
                    sum[nt] += z;
                    sq[nt] = fmaf(z, z, sq[nt]);
                }
            }
        }
    }
    // stats reduce: across quads (channels are col = nt*16 + r16)
#pragma unroll
    for (int nt = 0; nt < 4; ++nt) {
        sum[nt] += __shfl_xor(sum[nt], 16, 64);
        sum[nt] += __shfl_xor(sum[nt], 32, 64);
        sq[nt] += __shfl_xor(sq[nt], 16, 64);
        sq[nt] += __shfl_xor(sq[nt], 32, 64);
    }
    if (l < 16) {
#pragma unroll
        for (int nt = 0; nt < 4; ++nt) {
            atomicAdd(&sred[nt * 16 + l], sum[nt]);
            atomicAdd(&sred[64 + nt * 16 + l], sq[nt]);
        }
    }
    __syncthreads();
    if (tid < 128) atomicAdd(&spread[(bn & (SPREAD - 1)) * 128 + tid], sred[tid]);

    if (POOL) {
        int u = tid & 63;
        float pm = -3.402823e38f;
        for (int k = wv; k < NM1; k += 4) {
            int dst = dstcol(n, k);
            float wval;
            if (FIRST) wval = lrelu(fmaf(adjrow[dst], e0wL[u], e0bL[u]));
            else wval = w[((size_t)bn * NM1 + k) * Uu + u];
            float sg = 1.f / (1.f + __expf(-wval));
            pm = fmaxf(pm, sg * x2[(size_t)(b * Nn + dst) * Uu + u]);
        }
        pred[wv][u] = pm;
        __syncthreads();
        if (tid < Uu)
            pooled[(size_t)bn * Uu + tid] =
                fmaxf(fmaxf(pred[0][tid], pred[1][tid]), fmaxf(pred[2][tid], pred[3][tid]));
    }
}

// finalize w-path BN: wss[u]=scale, wss[64+u]=shift
__global__ void k_finw(const float* __restrict__ spread, const float* __restrict__ g,
                       const float* __restrict__ bb, float* __restrict__ wss) {
    int u = threadIdx.x;
    float s = 0.f, sq = 0.f;
    for (int p = 0; p < SPREAD; ++p) {
        s += spread[p * 128 + u];
        sq += spread[p * 128 + 64 + u];
    }
    const float Mf = (float)((size_t)Bb * Nn * NM1);
    float mean = s / Mf;
    float var = fmaxf(sq / Mf - mean * mean, 0.f);
    float inv = rsqrtf(var + EPSBN);
    float scale = g[u] * inv;
    wss[u] = scale;
    wss[64 + u] = bb[u] - mean * scale;
}

// h update: h += lrelu(bn(x1 + pooled)); one block per channel
__global__ void k_hup(const float* __restrict__ x1, const float* __restrict__ pooled,
                      const float* __restrict__ g, const float* __restrict__ bb,
                      float* __restrict__ h) {
    __shared__ float red[256], red2[256];
    int ch = blockIdx.x;
    int t = threadIdx.x;
    float s = 0.f, sq = 0.f;
    for (int bn = t; bn < Bb * Nn; bn += 256) {
        float v = x1[bn * Uu + ch] + pooled[bn * Uu + ch];
        s += v;
        sq = fmaf(v, v, sq);
    }
    red[t] = s;
    red2[t] = sq;
    __syncthreads();
    for (int off = 128; off; off >>= 1) {
        if (t < off) { red[t] += red[t + off]; red2[t] += red2[t + off]; }
        __syncthreads();
    }
    const float Mf = (float)(Bb * Nn);
    float mean = red[0] / Mf;
    float var = fmaxf(red2[0] / Mf - mean * mean, 0.f);
    float inv = rsqrtf(var + EPSBN);
    float scale = g[ch] * inv;
    float shift = bb[ch] - mean * scale;
    for (int bn = t; bn < Bb * Nn; bn += 256) {
        float v = x1[bn * Uu + ch] + pooled[bn * Uu + ch];
        h[bn * Uu + ch] += lrelu(fmaf(v, scale, shift));
    }
}

// --- MFMA pass 2: recompute z, apply BN + lrelu + residual; write w or final dot ---
template <bool FIRST, bool LAST>
__global__ __launch_bounds__(256, 4) void k_p2(
    float* __restrict__ w, const float* __restrict__ adj,
    const float* __restrict__ ew, const float* __restrict__ ebias,
    const float* __restrict__ e0w, const float* __restrict__ e0b,
    const float* __restrict__ x3, const float* __restrict__ x4,
    const float* __restrict__ wss, const float* __restrict__ elw,
    const float* __restrict__ elb, float* __restrict__ out) {
    __shared__ __align__(16) f16 Et[Uu * ET_STRIDE];
    __shared__ float c2[Uu];
    __shared__ float e0wL[Uu], e0bL[Uu];

    int bn = blockIdx.x;
    int b = bn / Nn, n = bn % Nn;
    int tid = threadIdx.x;
    int l = tid & 63, wv = tid >> 6;
    int r16 = l & 15, q = l >> 4;

    {
        int u = tid & 63, g = tid >> 6;
#pragma unroll
        for (int pp = 0; pp < 8; ++pp) {
            int jp = g + pp * 4;
            f16x2 pk;
            pk.x = (f16)ew[(2 * jp) * Uu + u];
            pk.y = (f16)ew[(2 * jp + 1) * Uu + u];
            *(f16x2*)&Et[u * ET_STRIDE + 2 * jp] = pk;
        }
    }
    if (tid < Uu) c2[tid] = ebias[tid] + x3[(size_t)bn * Uu + tid];
    if (FIRST && tid < Uu) { e0wL[tid] = e0w[tid]; e0bL[tid] = e0b[tid]; }
    __syncthreads();

    f16x8 Bf[2][4];
#pragma unroll
    for (int hh = 0; hh < 2; ++hh)
#pragma unroll
        for (int nt = 0; nt < 4; ++nt)
            Bf[hh][nt] = *(const f16x8*)&Et[(nt * 16 + r16) * ET_STRIDE + hh * 32 + q * 8];

    float scale_c[4], shift_c[4], elw_c[4];
#pragma unroll
    for (int nt = 0; nt < 4; ++nt) {
        scale_c[nt] = wss[nt * 16 + r16];
        shift_c[nt] = wss[64 + nt * 16 + r16];
        if (LAST) elw_c[nt] = elw[nt * 16 + r16];
    }
    float elb0 = LAST ? elb[0] : 0.f;

    const float* adjrow = adj + (size_t)bn * Nn;

    for (int mt = wv; mt < 13; mt += 4) {
        int row = mt * 16 + r16;
        bool rv = row < NM1;
        f16x8 A0 = (f16x8){0, 0, 0, 0, 0, 0, 0, 0};
        f16x8 A1 = (f16x8){0, 0, 0, 0, 0, 0, 0, 0};
        if (rv) {
            if (FIRST) {
                float av = adjrow[dstcol(n, row)];
#pragma unroll
                for (int j = 0; j < 8; ++j) {
                    A0[j] = (f16)lrelu(fmaf(av, e0wL[q * 8 + j], e0bL[q * 8 + j]));
                    A1[j] = (f16)lrelu(fmaf(av, e0wL[32 + q * 8 + j], e0bL[32 + q * 8 + j]));
                }
            } else {
                const float* wrow = w + ((size_t)bn * NM1 + row) * Uu;
                float4 p0 = *(const float4*)(wrow + q * 8);
                float4 p1 = *(const float4*)(wrow + q * 8 + 4);
                float4 p2 = *(const float4*)(wrow + 32 + q * 8);
                float4 p3 = *(const float4*)(wrow + 32 + q * 8 + 4);
                A0[0] = (f16)p0.x; A0[1] = (f16)p0.y; A0[2] = (f16)p0.z; A0[3] = (f16)p0.w;
                A0[4] = (f16)p1.x; A0[5] = (f16)p1.y; A0[6] = (f16)p1.z; A0[7] = (f16)p1.w;
                A1[0] = (f16)p2.x; A1[1] = (f16)p2.y; A1[2] = (f16)p2.z; A1[3] = (f16)p2.w;
                A1[4] = (f16)p3.x; A1[5] = (f16)p3.y; A1[6] = (f16)p3.z; A1[7] = (f16)p3.w;
            }
        }
        floatx4 acc[4];
#pragma unroll
        for (int nt = 0; nt < 4; ++nt) {
            acc[nt] = (floatx4){0.f, 0.f, 0.f, 0.f};
            acc[nt] = __builtin_amdgcn_mfma_f32_16x16x32_f16(A0, Bf[0][nt], acc[nt], 0, 0, 0);
            acc[nt] = __builtin_amdgcn_mfma_f32_16x16x32_f16(A1, Bf[1][nt], acc[nt], 0, 0, 0);
        }
#pragma unroll
        for (int rr = 0; rr < 4; ++rr) {
            int k = mt * 16 + q * 4 + rr;
            if (k < NM1) {
                int dst = dstcol(n, k);
                const float* x4r = x4 + (size_t)(b * Nn + dst) * Uu;
                float adv = 0.f;
                if (FIRST) adv = adjrow[dst];
                float tsum = 0.f;
#pragma unroll
                for (int nt = 0; nt < 4; ++nt) {
                    int u = nt * 16 + r16;
                    float z = acc[nt][rr] + c2[u] + x4r[u];
                    float wold;
                    if (FIRST) wold = lrelu(fmaf(adv, e0wL[u], e0bL[u]));
                    else wold = w[((size_t)bn * NM1 + k) * Uu + u];
                    float wnew = wold + lrelu(fmaf(z, scale_c[nt], shift_c[nt]));
                    if (!LAST) w[((size_t)bn * NM1 + k) * Uu + u] = wnew;
                    else tsum = fmaf(wnew, elw_c[nt], tsum);
                }
                if (LAST) {
                    tsum += __shfl_xor(tsum, 1, 64);
                    tsum += __shfl_xor(tsum, 2, 64);
                    tsum += __shfl_xor(tsum, 4, 64);
                    tsum += __shfl_xor(tsum, 8, 64);
                    if (r16 == 0) out[(size_t)bn * Nn + dst] = tsum + elb0;
                }
            }
        }
    }
    if (LAST && tid == 0) out[(size_t)bn * Nn + n] = 0.f;
}

extern "C" void kernel_launch(void* const* d_in, const int* in_sizes, int n_in,
                              void* d_out, int out_size, void* d_ws, size_t ws_size,
                              hipStream_t stream) {
    const float* x = (const float*)d_in[0];
    const float* adj = (const float*)d_in[1];
    const float* vl0w = (const float*)d_in[2];
    const float* vl0b = (const float*)d_in[3];
    const float* vw1 = (const float*)d_in[4];
    const float* vb1 = (const float*)d_in[5];
    const float* vw2 = (const float*)d_in[6];
    const float* vb2 = (const float*)d_in[7];
    const float* vw3 = (const float*)d_in[8];
    const float* vb3 = (const float*)d_in[9];
    const float* vw4 = (const float*)d_in[10];
    const float* vb4 = (const float*)d_in[11];
    const float* vbng = (const float*)d_in[12];
    const float* vbnb = (const float*)d_in[13];
    const float* e0w = (const float*)d_in[14];
    const float* e0b = (const float*)d_in[15];
    const float* ew = (const float*)d_in[16];
    const float* eb = (const float*)d_in[17];
    const float* ebng = (const float*)d_in[18];
    const float* ebnb = (const float*)d_in[19];
    const float* elw = (const float*)d_in[20];
    const float* elb = (const float*)d_in[21];
    float* out = (float*)d_out;

    float* ws = (float*)d_ws;
    float* w = ws;                        // 40,755,200 floats
    float* h = ws + 40755200;             // 204,800
    float* x1 = h + 204800;
    float* x2b = x1 + 204800;
    float* x3b = x2b + 204800;
    float* x4b = x3b + 204800;
    float* pooled = x4b + 204800;
    float* spread = pooled + 204800;      // SPREAD*128
    float* wss = spread + SPREAD * 128;   // 128

    const int GRID = Bb * Nn;  // 3200

    k_h0<<<800, 256, 0, stream>>>(x, vl0w, vl0b, h);

    // ---- layer 0 ----
    k_xvec<<<GRID, 64, 0, stream>>>(h, vw1, vb1, vw2, vb2, vw3, vb3, vw4, vb4,
                                    x1, x2b, x3b, x4b, spread);
    k_p1<true, true><<<GRID, 256, 0, stream>>>(w, adj, ew, eb, e0w, e0b, x2b,
                                               x3b, x4b, pooled, spread);
    k_finw<<<1, 64, 0, stream>>>(spread, ebng, ebnb, wss);
    k_hup<<<64, 256, 0, stream>>>(x1, pooled, vbng, vbnb, h);
    k_p2<true, false><<<GRID, 256, 0, stream>>>(w, adj, ew, eb, e0w, e0b, x3b,
                                                x4b, wss, elw, elb, out);

    // ---- layer 1 ----
    k_xvec<<<GRID, 64, 0, stream>>>(h, vw1 + 4096, vb1 + 64, vw2 + 4096, vb2 + 64,
                                    vw3 + 4096, vb3 + 64, vw4 + 4096, vb4 + 64,
                                    x1, x2b, x3b, x4b, spread);
    k_p1<false, true><<<GRID, 256, 0, stream>>>(w, adj, ew + 4096, eb + 64, e0w,
                                                e0b, x2b, x3b, x4b, pooled, spread);
    k_finw<<<1, 64, 0, stream>>>(spread, ebng + 64, ebnb + 64, wss);
    k_hup<<<64, 256, 0, stream>>>(x1, pooled, vbng + 64, vbnb + 64, h);
    k_p2<false, false><<<GRID, 256, 0, stream>>>(w, adj, ew + 4096, eb + 64, e0w,
                                                 e0b, x3b, x4b, wss, elw, elb, out);

    // ---- layer 2 ----
    k_xvec<<<GRID, 64, 0, stream>>>(h, vw1 + 8192, vb1 + 128, vw2 + 8192, vb2 + 128,
                                    vw3 + 8192, vb3 + 128, vw4 + 8192, vb4 + 128,
                                    x1, x2b, x3b, x4b, spread);
    k_p1<false, false><<<GRID, 256, 0, stream>>>(w, adj, ew + 8192, eb + 128, e0w,
                                                 e0b, x2b, x3b, x4b, pooled, spread);
    k_finw<<<1, 64, 0, stream>>>(spread, ebng + 128, ebnb + 128, wss);
    k_p2<false, true><<<GRID, 256, 0, stream>>>(w, adj, ew + 8192, eb + 128, e0w,
                                                e0b, x3b, x4b, wss, elw, elb, out);
}